// Round 12
// baseline (119.681 us; speedup 1.0000x reference)
//
#include <hip/hip_runtime.h>
#include <hip/hip_bf16.h>

// ChebConv_17841294148274. f32 in / f32 out (verified r3).
// out[(r*8+g)*192+j'] = sum_k Z[r][g][k]*W2[k][j'] + bias,
// Z[r][g][k] = sum_{e in row r} val_e * x_flat[col_e*512 + g*64 + k].
// r12: fuse gather+GEMM. Block = (16 vertex rows, g): gathers Z into LDS,
// barrier, MFMA from LDS, store out. 3 graph nodes (memset, scatter, fused).
#define NV      2048
#define NNZ_    98304
#define KDIM    64
#define WCOLS   192
#define BUCKET  128           // slots per row (Poisson(48) -> overflow ~1e-20)

typedef __attribute__((ext_vector_type(8))) short  short8;
typedef __attribute__((ext_vector_type(8))) unsigned short ushort8;
typedef __attribute__((ext_vector_type(4))) float  float4v;

__device__ __forceinline__ unsigned short f2b(float f) {
    return __bfloat16_as_ushort(__float2bfloat16(f));
}

// ---- Scatter edges into row buckets + (last block) W^T to bf16 ------------
// sedge[r*BUCKET + slot] = {col*512 (f32 offset into x), val bits}.
__global__ __launch_bounds__(256) void scatter_kernel(
    const int4* __restrict__ rows4, const int4* __restrict__ cols4,
    const float4* __restrict__ vals4, const float* __restrict__ wf,
    int* __restrict__ cnt, int2* __restrict__ sedge,
    unsigned short* __restrict__ wt)
{
    if (blockIdx.x == NNZ_ / 1024) {
        // wt[n*64+k] = bf16(W2[k][n]); W2 flat [64][192].
        for (int i = 0; i < 48; i++) {
            const int e = threadIdx.x + 256 * i;       // [0,12288)
            const int k = e / WCOLS, n = e - k * WCOLS;
            wt[n * KDIM + k] = f2b(wf[e]);
        }
        return;
    }
    const int t = blockIdx.x * 256 + threadIdx.x;      // [0, 24576)
    const int4   r = rows4[t];
    const int4   c = cols4[t];
    const float4 v = vals4[t];
    int p;
    p = atomicAdd(&cnt[r.x], 1); if (p < BUCKET) sedge[r.x * BUCKET + p] = make_int2(c.x * 512, __float_as_int(v.x));
    p = atomicAdd(&cnt[r.y], 1); if (p < BUCKET) sedge[r.y * BUCKET + p] = make_int2(c.y * 512, __float_as_int(v.y));
    p = atomicAdd(&cnt[r.z], 1); if (p < BUCKET) sedge[r.z * BUCKET + p] = make_int2(c.z * 512, __float_as_int(v.z));
    p = atomicAdd(&cnt[r.w], 1); if (p < BUCKET) sedge[r.w * BUCKET + p] = make_int2(c.w * 512, __float_as_int(v.w));
}

// ---- Fused gather + MFMA GEMM. Grid 1024 = 128 row-groups x 8 g. ----------
// g = blk&7 pins each g-slab to one XCD (slab x set = 1.57MB < 4MB L2).
// Phase A: wave w gathers rows 4w..4w+3 (r8's proven int4-pair loop),
// Z -> LDS. Phase B: one 16x192 MFMA tile from LDS (A = Zs), K=64.
// Frags (HW-verified m89/m91): A[m=lane&15][k=(lane>>4)*8+j]; B same with
// n=lane&15; C/D col=lane&15, row=(lane>>4)*4+reg. LDS rows padded to 72
// shorts -> 2-way bank aliasing only (free).
__global__ __launch_bounds__(256) void fused_kernel(
    const float* __restrict__ xf,
    const int* __restrict__ cnt,
    const int2* __restrict__ sedge,
    const unsigned short* __restrict__ wt,
    const float* __restrict__ bias,
    float* __restrict__ out)
{
    __shared__ unsigned short Wt[WCOLS * 72];   // 27.6 KB
    __shared__ unsigned short Zs[16 * 72];      //  2.3 KB
    const int b    = blockIdx.x;
    const int tid  = threadIdx.x;
    const int g    = b & 7;
    const int r0   = (b >> 3) * 16;             // vertex rows r0..r0+15
    const int w    = tid >> 6;
    const int lane = tid & 63;

#pragma unroll
    for (int u = 0; u < 6; u++) {   // stage W^T: 1536 ushort8 chunks
        const int ch = tid + 256 * u;              // [0,1536) -> 192 rows x 64 k
        const ushort8 p = *(const ushort8*)(wt + ch * 8);
        const int row = ch >> 3, col = (ch & 7) * 8;
        *(ushort8*)&Wt[row * 72 + col] = p;
    }

    // Phase A: gather 4 rows per wave (fixed g), lane owns k.
    {
        const int off = g * KDIM + lane;
#pragma unroll
        for (int s = 0; s < 4; s++) {
            const int lr  = w * 4 + s;             // local row 0..15
            const int row = r0 + lr;
            int n = cnt[row];
            if (n > BUCKET) n = BUCKET;
            const int4* se2 = (const int4*)(sedge + row * BUCKET);
            float acc = 0.f;
            int i = 0;
            for (; i + 8 <= n; i += 8) {
                const int4 ea = se2[(i >> 1)    ];
                const int4 eb = se2[(i >> 1) + 1];
                const int4 ec = se2[(i >> 1) + 2];
                const int4 ed = se2[(i >> 1) + 3];
                const float x0 = xf[ea.x + off], x1 = xf[ea.z + off];
                const float x2 = xf[eb.x + off], x3 = xf[eb.z + off];
                const float x4 = xf[ec.x + off], x5 = xf[ec.z + off];
                const float x6 = xf[ed.x + off], x7 = xf[ed.z + off];
                acc += __int_as_float(ea.y) * x0 + __int_as_float(ea.w) * x1
                     + __int_as_float(eb.y) * x2 + __int_as_float(eb.w) * x3
                     + __int_as_float(ec.y) * x4 + __int_as_float(ec.w) * x5
                     + __int_as_float(ed.y) * x6 + __int_as_float(ed.w) * x7;
            }
            const int2* se = (const int2*)se2;
            for (; i < n; i++) {
                const int2 e = se[i];
                acc += __int_as_float(e.y) * xf[e.x + off];
            }
            Zs[lr * 72 + lane] = f2b(acc);
        }
    }
    __syncthreads();

    // Phase B: MFMA. Wave w covers n-tiles 3w..3w+2.
    {
        const int q = lane >> 4;
        const int c = lane & 15;
        const short8 a0 = *(const short8*)&Zs[c * 72 + q * 8];
        const short8 a1 = *(const short8*)&Zs[c * 72 + 32 + q * 8];

#pragma unroll
        for (int t = 0; t < 3; t++) {
            const int nt = w * 3 + t;
            const short8 b0 = *(const short8*)&Wt[(nt * 16 + c) * 72 + q * 8];
            const short8 b1 = *(const short8*)&Wt[(nt * 16 + c) * 72 + 32 + q * 8];
            float4v d = {0.f, 0.f, 0.f, 0.f};
            d = __builtin_amdgcn_mfma_f32_16x16x32_bf16(a0, b0, d, 0, 0, 0);
            d = __builtin_amdgcn_mfma_f32_16x16x32_bf16(a1, b1, d, 0, 0, 0);
            const int col = nt * 16 + c;
            const float bb = bias[col & 63];
#pragma unroll
            for (int r = 0; r < 4; r++) {
                const size_t orow = (size_t)(r0 + q * 4 + r) * 8 + g;
                out[orow * WCOLS + col] = d[r] + bb;
            }
        }
    }
}

extern "C" void kernel_launch(void* const* d_in, const int* in_sizes, int n_in,
                              void* d_out, int out_size, void* d_ws, size_t ws_size,
                              hipStream_t stream) {
    const float* x    = (const float*)d_in[0];
    const float* wgt  = (const float*)d_in[1];
    const float* bias = (const float*)d_in[2];
    const float* fval = (const float*)d_in[3];
    const int* frow   = (const int*)d_in[4];
    const int* fcol   = (const int*)d_in[5];

    // Workspace layout:
    int* cnt = (int*)d_ws;                                    // 2048 ints
    int2* sedge = (int2*)(cnt + 2048);                        // 2048*128 int2 = 2 MB
    unsigned short* wt = (unsigned short*)(sedge + NV * BUCKET); // 12288 bf16

    hipMemsetAsync(cnt, 0, 2048 * sizeof(int), stream);
    scatter_kernel<<<NNZ_ / 1024 + 1, 256, 0, stream>>>(
        (const int4*)frow, (const int4*)fcol, (const float4*)fval, wgt,
        cnt, sedge, wt);
    fused_kernel  <<<NV / 2, 256, 0, stream>>>(x, cnt, sedge, wt, bias,
                                               (float*)d_out);
}

// Round 13
// 115.293 us; speedup vs baseline: 1.0381x; 1.0381x over previous
//
#include <hip/hip_runtime.h>
#include <hip/hip_bf16.h>

// ChebConv_17841294148274. f32 in / f32 out (verified r3).
// out[(r*8+g)*192+j'] = sum_k Z[r][g][k]*W2[k][j'] + bias,
// Z[r][g][k] = sum_{e in row r} val_e * x_flat[col_e*512 + g*64 + k].
// r13 = r12 fusion with restored TLP: 1024-thr blocks, 16 waves, one wave
// per (row,g) pair (16384 waves total, same as r11's spmmx). 3 graph nodes.
#define NV      2048
#define NNZ_    98304
#define KDIM    64
#define WCOLS   192
#define BUCKET  128           // slots per row (Poisson(48) -> overflow ~1e-20)

typedef __attribute__((ext_vector_type(8))) short  short8;
typedef __attribute__((ext_vector_type(8))) unsigned short ushort8;
typedef __attribute__((ext_vector_type(4))) float  float4v;

__device__ __forceinline__ unsigned short f2b(float f) {
    return __bfloat16_as_ushort(__float2bfloat16(f));
}

// ---- Scatter edges into row buckets + (last block) W^T to bf16 ------------
// sedge[r*BUCKET + slot] = {col*512 (f32 offset into x), val bits}.
__global__ __launch_bounds__(256) void scatter_kernel(
    const int4* __restrict__ rows4, const int4* __restrict__ cols4,
    const float4* __restrict__ vals4, const float* __restrict__ wf,
    int* __restrict__ cnt, int2* __restrict__ sedge,
    unsigned short* __restrict__ wt)
{
    if (blockIdx.x == NNZ_ / 1024) {
        // wt[n*64+k] = bf16(W2[k][n]); W2 flat [64][192].
        for (int i = 0; i < 48; i++) {
            const int e = threadIdx.x + 256 * i;       // [0,12288)
            const int k = e / WCOLS, n = e - k * WCOLS;
            wt[n * KDIM + k] = f2b(wf[e]);
        }
        return;
    }
    const int t = blockIdx.x * 256 + threadIdx.x;      // [0, 24576)
    const int4   r = rows4[t];
    const int4   c = cols4[t];
    const float4 v = vals4[t];
    int p;
    p = atomicAdd(&cnt[r.x], 1); if (p < BUCKET) sedge[r.x * BUCKET + p] = make_int2(c.x * 512, __float_as_int(v.x));
    p = atomicAdd(&cnt[r.y], 1); if (p < BUCKET) sedge[r.y * BUCKET + p] = make_int2(c.y * 512, __float_as_int(v.y));
    p = atomicAdd(&cnt[r.z], 1); if (p < BUCKET) sedge[r.z * BUCKET + p] = make_int2(c.z * 512, __float_as_int(v.z));
    p = atomicAdd(&cnt[r.w], 1); if (p < BUCKET) sedge[r.w * BUCKET + p] = make_int2(c.w * 512, __float_as_int(v.w));
}

// ---- Fused gather + MFMA GEMM. Grid 1024 = 128 row-groups x 8 g. ----------
// 1024 threads = 16 waves; wave w owns (row r0+w, g) — one pair per wave,
// 16384 concurrent gather chains (r11-equivalent TLP). g = blk&7 pins each
// g-slab to one XCD (slab x working set 1.57MB < 4MB L2). Phase B: waves
// 0..11 each compute one 16x16 n-tile from LDS. Frags (HW-verified m89/m91):
// A[m=lane&15][k=(lane>>4)*8+j]; B[n=lane&15][k same]; C/D col=lane&15,
// row=(lane>>4)*4+reg. LDS rows padded to 72 shorts (2-way aliasing, free).
__global__ __launch_bounds__(1024, 2) void fused_kernel(
    const float* __restrict__ xf,
    const int* __restrict__ cnt,
    const int2* __restrict__ sedge,
    const unsigned short* __restrict__ wt,
    const float* __restrict__ bias,
    float* __restrict__ out)
{
    __shared__ unsigned short Wt[WCOLS * 72];   // 27.6 KB
    __shared__ unsigned short Zs[16 * 72];      //  2.3 KB
    const int b    = blockIdx.x;
    const int tid  = threadIdx.x;
    const int g    = b & 7;
    const int r0   = (b >> 3) * 16;             // vertex rows r0..r0+15
    const int w    = tid >> 6;                  // wave 0..15
    const int lane = tid & 63;

    // stage W^T: 1536 ushort8 chunks over 1024 threads
    for (int ch = tid; ch < 1536; ch += 1024) {
        const ushort8 p = *(const ushort8*)(wt + ch * 8);
        const int row = ch >> 3, col = (ch & 7) * 8;
        *(ushort8*)&Wt[row * 72 + col] = p;
    }

    // Phase A: wave w gathers (row r0+w, g); lane owns k. r11's proven loop.
    {
        const int off = g * KDIM + lane;
        const int row = r0 + w;
        int n = cnt[row];
        if (n > BUCKET) n = BUCKET;
        const int4* se2 = (const int4*)(sedge + row * BUCKET);
        float acc = 0.f;
        int i = 0;
        for (; i + 8 <= n; i += 8) {
            const int4 ea = se2[(i >> 1)    ];
            const int4 eb = se2[(i >> 1) + 1];
            const int4 ec = se2[(i >> 1) + 2];
            const int4 ed = se2[(i >> 1) + 3];
            const float x0 = xf[ea.x + off], x1 = xf[ea.z + off];
            const float x2 = xf[eb.x + off], x3 = xf[eb.z + off];
            const float x4 = xf[ec.x + off], x5 = xf[ec.z + off];
            const float x6 = xf[ed.x + off], x7 = xf[ed.z + off];
            acc += __int_as_float(ea.y) * x0 + __int_as_float(ea.w) * x1
                 + __int_as_float(eb.y) * x2 + __int_as_float(eb.w) * x3
                 + __int_as_float(ec.y) * x4 + __int_as_float(ec.w) * x5
                 + __int_as_float(ed.y) * x6 + __int_as_float(ed.w) * x7;
        }
        const int2* se = (const int2*)se2;
        for (; i < n; i++) {
            const int2 e = se[i];
            acc += __int_as_float(e.y) * xf[e.x + off];
        }
        Zs[w * 72 + lane] = f2b(acc);
    }
    __syncthreads();

    // Phase B: waves 0..11 each do n-tile w (2 MFMA, K=64).
    if (w < 12) {
        const int q = lane >> 4;
        const int c = lane & 15;
        const short8 a0 = *(const short8*)&Zs[c * 72 + q * 8];
        const short8 a1 = *(const short8*)&Zs[c * 72 + 32 + q * 8];
        const short8 b0 = *(const short8*)&Wt[(w * 16 + c) * 72 + q * 8];
        const short8 b1 = *(const short8*)&Wt[(w * 16 + c) * 72 + 32 + q * 8];
        float4v d = {0.f, 0.f, 0.f, 0.f};
        d = __builtin_amdgcn_mfma_f32_16x16x32_bf16(a0, b0, d, 0, 0, 0);
        d = __builtin_amdgcn_mfma_f32_16x16x32_bf16(a1, b1, d, 0, 0, 0);
        const int col = w * 16 + c;
        const float bb = bias[col & 63];
#pragma unroll
        for (int r = 0; r < 4; r++) {
            const size_t orow = (size_t)(r0 + q * 4 + r) * 8 + g;
            out[orow * WCOLS + col] = d[r] + bb;
        }
    }
}

extern "C" void kernel_launch(void* const* d_in, const int* in_sizes, int n_in,
                              void* d_out, int out_size, void* d_ws, size_t ws_size,
                              hipStream_t stream) {
    const float* x    = (const float*)d_in[0];
    const float* wgt  = (const float*)d_in[1];
    const float* bias = (const float*)d_in[2];
    const float* fval = (const float*)d_in[3];
    const int* frow   = (const int*)d_in[4];
    const int* fcol   = (const int*)d_in[5];

    // Workspace layout:
    int* cnt = (int*)d_ws;                                    // 2048 ints
    int2* sedge = (int2*)(cnt + 2048);                        // 2048*128 int2 = 2 MB
    unsigned short* wt = (unsigned short*)(sedge + NV * BUCKET); // 12288 bf16

    hipMemsetAsync(cnt, 0, 2048 * sizeof(int), stream);
    scatter_kernel<<<NNZ_ / 1024 + 1, 256, 0, stream>>>(
        (const int4*)frow, (const int4*)fcol, (const float4*)fval, wgt,
        cnt, sedge, wt);
    fused_kernel  <<<NV / 2, 1024, 0, stream>>>(x, cnt, sedge, wt, bias,
                                                (float*)d_out);
}

// Round 14
// 107.489 us; speedup vs baseline: 1.1134x; 1.0726x over previous
//
#include <hip/hip_runtime.h>
#include <hip/hip_bf16.h>

// ChebConv_17841294148274. f32 in / f32 out (verified r3).
// out[(r*8+g)*192+j'] = sum_k Z[r][g][k]*W2[k][j'] + bias,
// Z[r][g][k] = sum_{e in row r} val_e * x_flat[col_e*512 + g*64 + k].
// r14 = r11 (108.9us best: 4 nodes, LDS edge staging) + spmmx unroll 8->16
// (3 latency batches per wave instead of 6 at mean degree 48).
#define NV      2048          // n_vertex
#define NNZ_    98304
#define KDIM    64            // contraction dim
#define WCOLS   192           // Ks*c_out
#define ZROWS   16384         // NV * 8
#define BUCKET  128           // slots per row (Poisson(48) -> overflow ~1e-20)

typedef __attribute__((ext_vector_type(8))) short  short8;
typedef __attribute__((ext_vector_type(8))) unsigned short ushort8;
typedef __attribute__((ext_vector_type(4))) float  float4v;

__device__ __forceinline__ float b2f(unsigned short h) {
    return __uint_as_float(((unsigned int)h) << 16);
}
__device__ __forceinline__ unsigned short f2b(float f) {
    return __bfloat16_as_ushort(__float2bfloat16(f));
}

// ---- Scatter edges into row buckets + (last block) W^T to bf16 ------------
// sedge[r*BUCKET + slot] = {col*512 (f32 offset into x), val bits}.
__global__ __launch_bounds__(256) void scatter_kernel(
    const int4* __restrict__ rows4, const int4* __restrict__ cols4,
    const float4* __restrict__ vals4, const float* __restrict__ wf,
    int* __restrict__ cnt, int2* __restrict__ sedge,
    unsigned short* __restrict__ wt)
{
    if (blockIdx.x == NNZ_ / 1024) {
        // wt[n*64+k] = bf16(W2[k][n]); W2 flat [64][192].
        for (int i = 0; i < 48; i++) {
            const int e = threadIdx.x + 256 * i;       // [0,12288)
            const int k = e / WCOLS, n = e - k * WCOLS;
            wt[n * KDIM + k] = f2b(wf[e]);
        }
        return;
    }
    const int t = blockIdx.x * 256 + threadIdx.x;      // [0, 24576)
    const int4   r = rows4[t];
    const int4   c = cols4[t];
    const float4 v = vals4[t];
    int p;
    p = atomicAdd(&cnt[r.x], 1); if (p < BUCKET) sedge[r.x * BUCKET + p] = make_int2(c.x * 512, __float_as_int(v.x));
    p = atomicAdd(&cnt[r.y], 1); if (p < BUCKET) sedge[r.y * BUCKET + p] = make_int2(c.y * 512, __float_as_int(v.y));
    p = atomicAdd(&cnt[r.z], 1); if (p < BUCKET) sedge[r.z * BUCKET + p] = make_int2(c.z * 512, __float_as_int(v.z));
    p = atomicAdd(&cnt[r.w], 1); if (p < BUCKET) sedge[r.w * BUCKET + p] = make_int2(c.w * 512, __float_as_int(v.w));
}

// ---- Stage 1: sparse gather on X. Grid 4096 x 4 waves; wave = one (row,g).
// g = blk&7 pins each g-slab to one XCD (slab x set = 1.57MB < 4MB L2).
// Edge bucket staged to LDS once per 64 edges (one wave-load), then inner
// loop reads metadata via LDS broadcast and issues 16 independent x loads
// per iteration (3 latency batches at mean degree 48).
__global__ __launch_bounds__(256) void spmmx_kernel(
    const float* __restrict__ xf,
    const int* __restrict__ cnt,
    const int2* __restrict__ sedge,
    unsigned short* __restrict__ zb)       // Z as bf16 [16384][64]
{
    __shared__ int2 se_lds[4][64];         // 2 KB, per-wave slice
    const int b    = blockIdx.x;
    const int g    = b & 7;
    const int w    = threadIdx.x >> 6;
    const int row  = (b >> 3) * 4 + w;
    const int lane = threadIdx.x & 63;

    int n = cnt[row];
    if (n > BUCKET) n = BUCKET;
    const int2* se = sedge + row * BUCKET;
    const int off = g * KDIM + lane;

    float acc = 0.f;
    for (int base = 0; base < n; base += 64) {
        const int m = (n - base < 64) ? (n - base) : 64;
        // stage up to 64 edges with one coalesced wave-load (wave-coherent
        // LDS: no barrier needed, compiler inserts lgkmcnt)
        const int li = (lane < m) ? (base + lane) : (base + m - 1);
        se_lds[w][lane] = se[li];

        int i = 0;
        for (; i + 16 <= m; i += 16) {
            int2 e[16];
#pragma unroll
            for (int u = 0; u < 16; u++) e[u] = se_lds[w][i + u];
            float x[16];
#pragma unroll
            for (int u = 0; u < 16; u++) x[u] = xf[e[u].x + off];
#pragma unroll
            for (int u = 0; u < 16; u++) acc += __int_as_float(e[u].y) * x[u];
        }
        for (; i + 8 <= m; i += 8) {
            const int2 e0 = se_lds[w][i    ], e1 = se_lds[w][i + 1];
            const int2 e2 = se_lds[w][i + 2], e3 = se_lds[w][i + 3];
            const int2 e4 = se_lds[w][i + 4], e5 = se_lds[w][i + 5];
            const int2 e6 = se_lds[w][i + 6], e7 = se_lds[w][i + 7];
            const float x0 = xf[e0.x + off], x1 = xf[e1.x + off];
            const float x2 = xf[e2.x + off], x3 = xf[e3.x + off];
            const float x4 = xf[e4.x + off], x5 = xf[e5.x + off];
            const float x6 = xf[e6.x + off], x7 = xf[e7.x + off];
            acc += __int_as_float(e0.y) * x0 + __int_as_float(e1.y) * x1
                 + __int_as_float(e2.y) * x2 + __int_as_float(e3.y) * x3
                 + __int_as_float(e4.y) * x4 + __int_as_float(e5.y) * x5
                 + __int_as_float(e6.y) * x6 + __int_as_float(e7.y) * x7;
        }
        for (; i < m; i++) {
            const int2 e = se_lds[w][i];
            acc += __int_as_float(e.y) * xf[e.x + off];
        }
    }
    zb[(size_t)(row * 8 + g) * KDIM + lane] = f2b(acc);
}

// ---- Stage 2 GEMM via MFMA: out[m][j'] = sum_k Z[m][k] W2[k][j'] + bias ----
// 256 blocks x 256 thr (4 waves). Block = 64 m-rows x 192 cols, K=64.
// LDS rows padded to 72 shorts -> 2-way bank aliasing only (free).
// Frags (HW-verified m89/m91): A[m=lane&15][k=(lane>>4)*8+j]; B same with
// n=lane&15; C/D col=lane&15, row=(lane>>4)*4+reg.
__global__ __launch_bounds__(256) void gemm2_kernel(
    const unsigned short* __restrict__ zb, const unsigned short* __restrict__ wt,
    const float* __restrict__ bias, float* __restrict__ out)
{
    __shared__ unsigned short Wt[WCOLS * 72];   // 192 x 72 = 27.6 KB
    __shared__ unsigned short Zs[64 * 72];      //  64 x 72 =  9.2 KB
    const int tid = threadIdx.x;
    const int m0  = blockIdx.x * 64;

#pragma unroll
    for (int u = 0; u < 2; u++) {   // stage Z-tile: 512 ushort8 chunks
        const int ch = tid + 256 * u;              // [0,512) -> 64 rows x 64 k
        const ushort8 p = *(const ushort8*)(zb + (size_t)m0 * KDIM + ch * 8);
        const int row = ch >> 3, col = (ch & 7) * 8;
        *(ushort8*)&Zs[row * 72 + col] = p;
    }
#pragma unroll
    for (int u = 0; u < 6; u++) {   // stage W^T: 1536 ushort8 chunks
        const int ch = tid + 256 * u;              // [0,1536) -> 192 rows x 64 k
        const ushort8 p = *(const ushort8*)(wt + ch * 8);
        const int row = ch >> 3, col = (ch & 7) * 8;
        *(ushort8*)&Wt[row * 72 + col] = p;
    }
    __syncthreads();

    const int lane = tid & 63;
    const int mt   = tid >> 6;          // wave id = m-tile 0..3
    const int q    = lane >> 4;         // quad 0..3
    const int c    = lane & 15;

    const short8 a0 = *(const short8*)&Zs[(mt * 16 + c) * 72 + q * 8];
    const short8 a1 = *(const short8*)&Zs[(mt * 16 + c) * 72 + 32 + q * 8];

    float4v acc[12];
#pragma unroll
    for (int nt = 0; nt < 12; nt++) {
        const short8 b0 = *(const short8*)&Wt[(nt * 16 + c) * 72 + q * 8];
        const short8 b1 = *(const short8*)&Wt[(nt * 16 + c) * 72 + 32 + q * 8];
        float4v d = {0.f, 0.f, 0.f, 0.f};
        d = __builtin_amdgcn_mfma_f32_16x16x32_bf16(a0, b0, d, 0, 0, 0);
        d = __builtin_amdgcn_mfma_f32_16x16x32_bf16(a1, b1, d, 0, 0, 0);
        acc[nt] = d;
    }

    const int rbase = m0 + mt * 16 + q * 4;
#pragma unroll
    for (int nt = 0; nt < 12; nt++) {
        const int col = nt * 16 + c;
        const float bb = bias[col & 63];
#pragma unroll
        for (int r = 0; r < 4; r++)
            out[(size_t)(rbase + r) * WCOLS + col] = acc[nt][r] + bb;
    }
}

extern "C" void kernel_launch(void* const* d_in, const int* in_sizes, int n_in,
                              void* d_out, int out_size, void* d_ws, size_t ws_size,
                              hipStream_t stream) {
    const float* x    = (const float*)d_in[0];
    const float* wgt  = (const float*)d_in[1];
    const float* bias = (const float*)d_in[2];
    const float* fval = (const float*)d_in[3];
    const int* frow   = (const int*)d_in[4];
    const int* fcol   = (const int*)d_in[5];

    // Workspace layout:
    int* cnt = (int*)d_ws;                                    // 2048 ints
    int2* sedge = (int2*)(cnt + 2048);                        // 2048*128 int2 = 2 MB
    unsigned short* wt = (unsigned short*)(sedge + NV * BUCKET); // 12288 bf16
    unsigned short* zb = wt + 12288;                          // 16384*64 bf16 = 2 MB

    hipMemsetAsync(cnt, 0, 2048 * sizeof(int), stream);
    scatter_kernel<<<NNZ_ / 1024 + 1, 256, 0, stream>>>(
        (const int4*)frow, (const int4*)fcol, (const float4*)fval, wgt,
        cnt, sedge, wt);
    spmmx_kernel <<<ZROWS / 4, 256, 0, stream>>>(x, cnt, sedge, zb);
    gemm2_kernel <<<ZROWS / 64, 256, 0, stream>>>(zb, wt, bias, (float*)d_out);
}